// Round 7
// baseline (37.663 us; speedup 1.0000x reference)
//
#include <hip/hip_runtime.h>

// PS-RoI-Align (torchvision ps_roi_align semantics).
// feat: [4, 784, 112, 112] fp32; rois: [K,5]; out: [K, 16, 7, 7] fp32.
//
// R6: persistent plane streaming with counted-vmcnt pipeline (T3/T4).
//   R5's __syncthreads drained vmcnt(0) INCLUDING the just-issued prefetch
//   -> ~900cyc HBM-idle bubble per ~4800cyc plane (~18%). Replace with:
//     stage(next)                      // 7 async global_load_lds per wave
//     s_waitcnt vmcnt(7)               // wait only for PREVIOUS plane's stage
//     s_barrier                        // all waves: buf[cur] fully landed
//     compute(cur)                     // LDS bilinear sampling
//     s_barrier                        // protect buf[cur] before next overwrite
//   -> prefetch stays in flight across barriers; HBM never idles.
//   Also: 224 blocks x exactly 14 contiguous planes (3136 = 224*14, no tail;
//   each block streams a contiguous 700KB of feat).
//   Staging padded to 56 chunks (7/wave uniform -> literal vmcnt); dummy
//   chunks 49..55 re-read global chunk 48 (no OOB) into an LDS pad region.

#define PP 7
#define SR 2
#define SCALEF 0.0625f

constexpr int Cc        = 784;             // Cout * P * P
constexpr int Hh        = 112;
constexpr int Ww        = 112;
constexpr int PLANE     = Hh * Ww;         // 12544 floats = 50176 B
constexpr int CHUNKS    = (PLANE * 4) / 1024;  // 49 real 1KB chunks
constexpr int CHUNKS_PAD= 56;              // 7 per wave x 8 waves
constexpr int PLANEPAD  = CHUNKS_PAD * 256;    // 14336 floats
constexpr int NBLK      = 224;             // 3136 / 14
constexpr int TPB       = 512;             // 8 waves
constexpr int RPT       = 2;               // rois per thread (K <= 1024)

__global__ __launch_bounds__(TPB) void psroi_persist_kernel(
    const float* __restrict__ feat,
    const float* __restrict__ rois,
    float* __restrict__ out,
    int K, int nplanes)
{
    __shared__ float buf[2][PLANEPAD];     // 114688 B

    int tid  = threadIdx.x;
    int wave = tid >> 6;
    int lane = tid & 63;

    // ---- parse roi params once per block into registers ----
    int   rb[RPT];
    float x1[RPT], y1[RPT], bsh[RPT], bsw[RPT];
#pragma unroll
    for (int j = 0; j < RPT; ++j) {
        int k = tid + j * TPB;
        if (k < K) {
            const float* r = rois + (size_t)k * 5;
            rb[j]  = (int)r[0];
            x1[j]  = r[1] * SCALEF - 0.5f;
            y1[j]  = r[2] * SCALEF - 0.5f;
            float rw = fmaxf(r[3] * SCALEF - 0.5f - x1[j], 0.1f);
            float rh = fmaxf(r[4] * SCALEF - 0.5f - y1[j], 0.1f);
            bsh[j] = rh * (1.0f / (float)PP);
            bsw[j] = rw * (1.0f / (float)PP);
        } else {
            rb[j] = -1;
        }
    }

    // ---- async stage one plane into buf[bi]: exactly 7 loads per wave ----
    auto stage = [&](int bi, int p) {
        const float* src = feat + (size_t)p * PLANE;
#pragma unroll
        for (int t = 0; t < 7; ++t) {
            int j  = wave + t * 8;                  // 0..55, 7 per wave
            int gj = j < CHUNKS ? j : CHUNKS - 1;   // dummy chunks re-read 48
            __builtin_amdgcn_global_load_lds(
                (const __attribute__((address_space(1))) void*)(src + gj * 256 + lane * 4),
                (__attribute__((address_space(3))) void*)(&buf[bi][j * 256]),
                16, 0, 0);
        }
    };

    // balanced contiguous partition (nplanes = 3136 -> 14 per block, rem 0)
    int per   = nplanes / NBLK;
    int rem   = nplanes % NBLK;
    int start = blockIdx.x * per + min((int)blockIdx.x, rem);
    int cnt   = per + ((int)blockIdx.x < rem ? 1 : 0);

    stage(0, start);                       // prologue prefetch
    int cur = 0;

    for (int i = 0; i < cnt; ++i) {
        int p = start + i;
        if (i + 1 < cnt) {
            stage(cur ^ 1, p + 1);         // keep next plane in flight
            asm volatile("s_waitcnt vmcnt(7)" ::: "memory");  // prev stage done
        } else {
            asm volatile("s_waitcnt vmcnt(0)" ::: "memory");  // final drain
        }
        __builtin_amdgcn_s_barrier();      // buf[cur] visible to all waves

        int b  = p / Cc;
        int c  = p % Cc;
        int pw = c % PP;
        int ph = (c % (PP * PP)) / PP;
        const float* pl = buf[cur];

#pragma unroll
        for (int j = 0; j < RPT; ++j) {
            if (rb[j] != b) continue;
            float acc = 0.0f;
#pragma unroll
            for (int iy = 0; iy < SR; ++iy) {
                float gy = ((float)iy + 0.5f) / (float)SR;
                float y  = y1[j] + ((float)ph + gy) * bsh[j];
                bool  vy = (y >= -1.0f) && (y <= (float)Hh);
                float yc = fminf(fmaxf(y, 0.0f), (float)(Hh - 1));
                int   yl = (int)yc;            // yc >= 0 -> trunc == floor
                int   yh = min(yl + 1, Hh - 1);
                float ly = yc - (float)yl;
                float hy = 1.0f - ly;
#pragma unroll
                for (int ix = 0; ix < SR; ++ix) {
                    float gx = ((float)ix + 0.5f) / (float)SR;
                    float x  = x1[j] + ((float)pw + gx) * bsw[j];
                    bool  vx = (x >= -1.0f) && (x <= (float)Ww);
                    float xc = fminf(fmaxf(x, 0.0f), (float)(Ww - 1));
                    int   xl = (int)xc;
                    int   xh = min(xl + 1, Ww - 1);
                    float lx = xc - (float)xl;
                    float hx = 1.0f - lx;

                    float v = hy * hx * pl[yl * Ww + xl]
                            + hy * lx * pl[yl * Ww + xh]
                            + ly * hx * pl[yh * Ww + xl]
                            + ly * lx * pl[yh * Ww + xh];
                    acc += (vy && vx) ? v : 0.0f;
                }
            }
            int k = tid + j * TPB;
            out[(size_t)k * Cc + c] = acc * (1.0f / (float)(SR * SR));
        }

        asm volatile("" ::: "memory");
        __builtin_amdgcn_s_barrier();      // all waves done reading buf[cur]
        cur ^= 1;
    }
}

extern "C" void kernel_launch(void* const* d_in, const int* in_sizes, int n_in,
                              void* d_out, int out_size, void* d_ws, size_t ws_size,
                              hipStream_t stream) {
    const float* feat = (const float*)d_in[0];
    const float* rois = (const float*)d_in[1];
    float* out = (float*)d_out;

    int K = in_sizes[1] / 5;
    int nplanes = in_sizes[0] / PLANE;          // N * Cc = 3136
    psroi_persist_kernel<<<NBLK, TPB, 0, stream>>>(feat, rois, out, K, nplanes);
}